// Round 2
// baseline (896.828 us; speedup 1.0000x reference)
//
#include <hip/hip_runtime.h>
#include <hip/hip_bf16.h>

#define TOPK 50
#define CAP 512
#define MQ 100000
#define HFLOOR 0.16f
#define HBIN 0.005f

typedef float f32x4 __attribute__((ext_vector_type(4)));
typedef __bf16 bf16x8 __attribute__((ext_vector_type(8)));
typedef unsigned short u16x8 __attribute__((ext_vector_type(8)));
typedef unsigned short u16x4 __attribute__((ext_vector_type(4)));

__device__ __forceinline__ unsigned short f2bf(float f) {
    unsigned int u = __float_as_uint(f);
    return (unsigned short)((u + 0x7fffu + ((u >> 16) & 1u)) >> 16);
}

// ---------------- K0: transpose W1/W2 to bf16 [C][K] ----------------
__global__ void k_transpose(const float* __restrict__ W1, const float* __restrict__ W2,
                            unsigned short* __restrict__ W1t, unsigned short* __restrict__ W2t) {
    int c = blockIdx.x & 255;
    int k = threadIdx.x;
    if (blockIdx.x < 256) W1t[c*256 + k] = f2bf(W1[k*256 + c]);
    else                  W2t[c*256 + k] = f2bf(W2[k*256 + c]);
}

// ---------------- K1: q = l2norm(cr@Wq + bq) in f64 ----------------
__global__ void k_qproj(const float* __restrict__ cr, const float* __restrict__ Wq,
                        const float* __restrict__ bq,
                        double* __restrict__ q64, unsigned short* __restrict__ qbf) {
    int row = blockIdx.x, d = threadIdx.x;
    __shared__ double xs[128];
    __shared__ double red[128];
    xs[d] = (double)cr[row*128 + d];
    __syncthreads();
    double s = (double)bq[d];
    #pragma unroll 4
    for (int i = 0; i < 128; ++i) s += xs[i] * (double)Wq[i*128 + d];
    red[d] = s * s;
    __syncthreads();
    for (int off = 64; off > 0; off >>= 1) {
        if (d < off) red[d] += red[d + off];
        __syncthreads();
    }
    double inv = 1.0 / fmax(sqrt(red[0]), 1e-12);
    double qv = s * inv;
    q64[row*128 + d] = qv;
    qbf[row*128 + d] = f2bf((float)qv);
}

// ---------------- K2: k_hi = bf16(l2norm(fq@Wk + bk)), invn f64 ----------------
__global__ __launch_bounds__(256) void k_kproj(const float* __restrict__ fq,
        const float* __restrict__ Wk, const float* __restrict__ bk,
        unsigned short* __restrict__ k_hi, double* __restrict__ invn) {
    __shared__ __align__(16) float wks[128*128];   // 64 KB
    __shared__ __align__(16) float fqs[128*129];   // 66 KB (padded rows: conflict-free)
    int t = threadIdx.x;
    long row0 = (long)blockIdx.x * 128;
    for (int j = 0; j < 16; ++j) {
        int id4 = t + 256*j;
        float4 v = reinterpret_cast<const float4*>(Wk)[id4];
        *reinterpret_cast<float4*>(&wks[id4*4]) = v;
    }
    for (int j = 0; j < 16; ++j) {
        int id4 = t + 256*j;
        int r = id4 >> 5;
        int c4 = (id4 & 31) << 2;
        float4 v = {0.f, 0.f, 0.f, 0.f};
        if (row0 + r < MQ) v = *reinterpret_cast<const float4*>(&fq[(row0 + r)*128 + c4]);
        fqs[r*129 + c4 + 0] = v.x;
        fqs[r*129 + c4 + 1] = v.y;
        fqs[r*129 + c4 + 2] = v.z;
        fqs[r*129 + c4 + 3] = v.w;
    }
    __syncthreads();
    const int ct = t & 15, rt = t >> 4;
    const int r0 = rt * 8, c0 = ct * 4;
    float acc[8][8];
    #pragma unroll
    for (int a = 0; a < 8; ++a)
        #pragma unroll
        for (int b = 0; b < 8; ++b) acc[a][b] = 0.f;
    #pragma unroll 2
    for (int i = 0; i < 128; ++i) {
        float4 w0 = *reinterpret_cast<const float4*>(&wks[i*128 + c0]);
        float4 w1 = *reinterpret_cast<const float4*>(&wks[i*128 + 64 + c0]);
        float a[8];
        #pragma unroll
        for (int rr = 0; rr < 8; ++rr) a[rr] = fqs[(r0+rr)*129 + i];
        #pragma unroll
        for (int rr = 0; rr < 8; ++rr) {
            acc[rr][0] = fmaf(a[rr], w0.x, acc[rr][0]);
            acc[rr][1] = fmaf(a[rr], w0.y, acc[rr][1]);
            acc[rr][2] = fmaf(a[rr], w0.z, acc[rr][2]);
            acc[rr][3] = fmaf(a[rr], w0.w, acc[rr][3]);
            acc[rr][4] = fmaf(a[rr], w1.x, acc[rr][4]);
            acc[rr][5] = fmaf(a[rr], w1.y, acc[rr][5]);
            acc[rr][6] = fmaf(a[rr], w1.z, acc[rr][6]);
            acc[rr][7] = fmaf(a[rr], w1.w, acc[rr][7]);
        }
    }
    float bkv[8];
    #pragma unroll
    for (int cc = 0; cc < 4; ++cc) { bkv[cc] = bk[c0+cc]; bkv[4+cc] = bk[64+c0+cc]; }
    #pragma unroll
    for (int rr = 0; rr < 8; ++rr)
        #pragma unroll
        for (int cc = 0; cc < 8; ++cc) acc[rr][cc] += bkv[cc];
    __syncthreads();                       // fqs dead -> reuse as f64 scratch
    double* npart = reinterpret_cast<double*>(fqs);
    #pragma unroll
    for (int rr = 0; rr < 8; ++rr) {
        double pn = 0.0;
        #pragma unroll
        for (int cc = 0; cc < 8; ++cc) pn += (double)acc[rr][cc] * (double)acc[rr][cc];
        npart[(r0+rr)*16 + ct] = pn;
    }
    __syncthreads();
    double* invd = npart + 128*16;
    if (t < 128) {
        double nn = 0.0;
        for (int k2 = 0; k2 < 16; ++k2) nn += npart[t*16 + k2];
        double iv = 1.0 / fmax(sqrt(nn), 1e-12);
        invd[t] = iv;
        if (row0 + t < MQ) invn[row0 + t] = iv;
    }
    __syncthreads();
    #pragma unroll
    for (int rr = 0; rr < 8; ++rr) {
        long row = row0 + r0 + rr;
        if (row < MQ) {
            float iv = (float)invd[r0 + rr];
            u16x4 o0, o1;
            #pragma unroll
            for (int cc = 0; cc < 4; ++cc) {
                o0[cc] = f2bf(acc[rr][cc] * iv);
                o1[cc] = f2bf(acc[rr][4+cc] * iv);
            }
            *reinterpret_cast<u16x4*>(&k_hi[row*128 + c0]) = o0;
            *reinterpret_cast<u16x4*>(&k_hi[row*128 + 64 + c0]) = o1;
        }
    }
}

// ---------------- K3: bf16 MFMA sims; HIST pass builds per-row histogram,
// ---------------- APPEND pass thresholds with per-row T ----------------
template<bool HIST>
__global__ __launch_bounds__(256) void k_sims_t(const unsigned short* __restrict__ qbf,
        const unsigned short* __restrict__ k_hi,
        int* __restrict__ rhist, const float* __restrict__ Trow,
        int* __restrict__ cnt, int* __restrict__ cand) {
    __shared__ unsigned short kt[64*128];   // 16 KB k-tile [64 cols][128 k]
    int t = threadIdx.x;
    int col0 = blockIdx.x * 64;
    for (int j = 0; j < 4; ++j) {
        int chunk = t + 256*j;
        int r = chunk >> 4, s = chunk & 15;
        u16x8 v = {0,0,0,0,0,0,0,0};
        long col = col0 + r;
        if (col < MQ) v = *reinterpret_cast<const u16x8*>(&k_hi[col*128 + s*8]);
        *reinterpret_cast<u16x8*>(&kt[r*128 + s*8]) = v;
    }
    __syncthreads();
    int w = t >> 6, l = t & 63;
    int lr = l & 15, lk = l >> 4;
    bf16x8 bfr[4];
    #pragma unroll
    for (int kk = 0; kk < 4; ++kk)
        bfr[kk] = *reinterpret_cast<const bf16x8*>(&kt[(w*16 + lr)*128 + kk*32 + lk*8]);
    int colg = col0 + w*16 + lr;
    for (int rg = 0; rg < 64; ++rg) {
        const unsigned short* qrow = qbf + (rg*16 + lr)*128 + lk*8;
        f32x4 acc = {0.f, 0.f, 0.f, 0.f};
        #pragma unroll
        for (int kk = 0; kk < 4; ++kk) {
            bf16x8 a = *reinterpret_cast<const bf16x8*>(qrow + kk*32);
            acc = __builtin_amdgcn_mfma_f32_16x16x32_bf16(a, bfr[kk], acc, 0, 0, 0);
        }
        if (colg < MQ) {
            #pragma unroll
            for (int i = 0; i < 4; ++i) {
                float v = acc[i];
                int r = rg*16 + lk*4 + i;
                if (HIST) {
                    int b = (int)floorf((v - HFLOOR) * 200.0f);
                    if (b >= 0) {
                        if (b > 63) b = 63;
                        atomicAdd(&rhist[r*64 + b], 1);
                    }
                } else {
                    if (v >= Trow[r]) {
                        int pos = atomicAdd(&cnt[r], 1);
                        if (pos < CAP) cand[r*CAP + pos] = colg;
                    }
                }
            }
        }
    }
}

// ---------------- K3b: per-row threshold from histogram ----------------
__global__ void k_pick(const int* __restrict__ rhist, float* __restrict__ Trow) {
    int r = blockIdx.x * 256 + threadIdx.x;
    if (r < 1024) {
        int cum = 0;
        float T = HFLOOR - HBIN;   // fallback floor
        for (int b = 63; b >= 0; --b) {
            cum += rhist[r*64 + b];
            if (cum >= TOPK) { T = HFLOOR + HBIN * b - HBIN; break; }
        }
        Trow[r] = T;
    }
}

// ---------------- K4: exact f64 re-score, top-50, softmax, context ----------------
__global__ __launch_bounds__(256) void k_select(
        const double* __restrict__ q64, const float* __restrict__ Wk,
        const float* __restrict__ bk, const float* __restrict__ fq,
        const double* __restrict__ invn, const int* __restrict__ sq,
        const int* __restrict__ sid, const int* __restrict__ cnt,
        const int* __restrict__ cand,
        float* __restrict__ attn_g, int* __restrict__ tidx_g, int* __restrict__ used_g,
        float* __restrict__ out_ctx, float* __restrict__ out_used,
        const float* __restrict__ fb_ctx) {
    __shared__ double qs[128];
    __shared__ double wqr[128];
    __shared__ double qb_s;
    __shared__ double vals[CAP];
    __shared__ int cidx[CAP];
    __shared__ double selv[TOPK];
    __shared__ int seli[TOPK];
    __shared__ float attn_s[TOPK];
    __shared__ int used_s;
    int row = blockIdx.x, t = threadIdx.x;
    if (t < 128) qs[t] = q64[row*128 + t];
    __syncthreads();
    if (t < 128) {
        double s = 0.0;
        for (int d = 0; d < 128; ++d) s += (double)Wk[t*128 + d] * qs[d];
        wqr[t] = s;
    }
    if (t == 0) {
        double s = 0.0;
        for (int d = 0; d < 128; ++d) s += qs[d] * (double)bk[d];
        qb_s = s;
    }
    if (t < TOPK) { selv[t] = -1e290; seli[t] = 0; }
    __syncthreads();
    int n = cnt[row]; if (n > CAP) n = CAP;
    int myses = sid[row];
    for (int j = t; j < n; j += 256) {
        int c = cand[row*CAP + j];
        cidx[j] = c;
        double v;
        if (sq[c] == myses) v = -1e300;
        else {
            double s = qb_s;
            const float4* xr4 = reinterpret_cast<const float4*>(fq + (long)c*128);
            for (int i4 = 0; i4 < 32; ++i4) {
                float4 x4 = xr4[i4];
                s += (double)x4.x * wqr[i4*4+0] + (double)x4.y * wqr[i4*4+1]
                   + (double)x4.z * wqr[i4*4+2] + (double)x4.w * wqr[i4*4+3];
            }
            v = s * invn[c];
        }
        vals[j] = v;
    }
    __syncthreads();
    for (int j = t; j < n; j += 256) {
        double v = vals[j]; int ci = cidx[j];
        int rk = 0;
        for (int m2 = 0; m2 < n; ++m2) {
            double vm = vals[m2];
            rk += (vm > v) || (vm == v && cidx[m2] < ci);
        }
        if (rk < TOPK) { selv[rk] = v; seli[rk] = ci; }
    }
    __syncthreads();
    if (t == 0) {
        double vmax = -1.0e308;
        for (int r = 0; r < TOPK; ++r)
            if (selv[r] > -1e250 && selv[r] > vmax) vmax = selv[r];
        float ssum = 0.f;
        for (int r = 0; r < TOPK; ++r) {
            float ev = 0.f;
            if (selv[r] > -1e250) ev = expf((float)((selv[r] - vmax) * (1.0/0.07)));
            attn_s[r] = ev; ssum += ev;
        }
        float invs = (ssum > 0.f) ? 1.0f/ssum : 0.0f;
        for (int r = 0; r < TOPK; ++r) attn_s[r] *= invs;
        used_s = (ssum > 0.f) ? 1 : 0;
        used_g[row] = used_s;
    }
    __syncthreads();
    int used = used_s;
    if (t < TOPK) { attn_g[row*TOPK + t] = attn_s[t]; tidx_g[row*TOPK + t] = seli[t]; }
    if (t < 128) {
        float cacc = 0.f;
        for (int r = 0; r < TOPK; ++r) cacc += attn_s[r] * fq[(long)seli[r]*128 + t];
        out_ctx[row*128 + t] = used ? cacc : fb_ctx[t];
    }
    if (t == 0) out_used[row] = used ? 1.0f : 0.0f;
}

// ---------------- K5: fused MLP (gather -> gelu(x@W1+b1)@W2+b2 -> attn-reduce) ----------------
__global__ __launch_bounds__(256) void k_mlp(
        const float* __restrict__ fq, const float* __restrict__ item_emb,
        const int* __restrict__ tq,
        const unsigned short* __restrict__ W1t, const unsigned short* __restrict__ W2t,
        const float* __restrict__ b1, const float* __restrict__ b2,
        const float* __restrict__ attn_g, const int* __restrict__ tidx_g,
        const int* __restrict__ used_g,
        const float* __restrict__ fb_sum, float* __restrict__ out_sum) {
    __shared__ __align__(16) unsigned short xs[64*256];   // 32 KB, reused for h
    __shared__ float attn_s[64];
    __shared__ int tgt_s[64];
    __shared__ int tix_s[64];
    int b = blockIdx.x, t = threadIdx.x;
    if (t < 64) {
        float a = 0.f; int ti = 0;
        if (t < TOPK) { a = attn_g[b*TOPK + t]; ti = tidx_g[b*TOPK + t]; }
        attn_s[t] = a; tix_s[t] = ti;
        int tg = 0;
        if (t < TOPK) { tg = tq[ti]; if (tg < 0) tg = 0; }
        tgt_s[t] = tg;
    }
    __syncthreads();
    for (int j = 0; j < 8; ++j) {
        int chunk = t + 256*j;
        int r = chunk >> 5, s = chunk & 31;
        int sp = s ^ (r & 7);
        u16x8 o = {0,0,0,0,0,0,0,0};
        if (r < TOPK) {
            int c0 = s * 8;
            const float* src = (c0 < 128) ? (fq + (long)tix_s[r]*128 + c0)
                                          : (item_emb + (long)tgt_s[r]*128 + (c0 - 128));
            float4 v0 = *reinterpret_cast<const float4*>(src);
            float4 v1 = *reinterpret_cast<const float4*>(src + 4);
            o[0] = f2bf(v0.x); o[1] = f2bf(v0.y); o[2] = f2bf(v0.z); o[3] = f2bf(v0.w);
            o[4] = f2bf(v1.x); o[5] = f2bf(v1.y); o[6] = f2bf(v1.z); o[7] = f2bf(v1.w);
        }
        *reinterpret_cast<u16x8*>(&xs[(r*32 + sp)*8]) = o;
    }
    __syncthreads();
    int w = t >> 6, l = t & 63, lr = l & 15, lk = l >> 4;
    int wbase = w * 64;
    f32x4 zero4 = {0.f, 0.f, 0.f, 0.f};
    f32x4 acc[4][4];
    #pragma unroll
    for (int rt = 0; rt < 4; ++rt)
        #pragma unroll
        for (int ctl = 0; ctl < 4; ++ctl) acc[rt][ctl] = zero4;
    #pragma unroll
    for (int kk = 0; kk < 8; ++kk) {
        bf16x8 av[4];
        #pragma unroll
        for (int rt = 0; rt < 4; ++rt) {
            int r = rt*16 + lr;
            int sp = (kk*4 + lk) ^ (r & 7);
            av[rt] = *reinterpret_cast<const bf16x8*>(&xs[(r*32 + sp)*8]);
        }
        #pragma unroll
        for (int ctl = 0; ctl < 4; ++ctl) {
            int col = wbase + ctl*16 + lr;
            bf16x8 bv = *reinterpret_cast<const bf16x8*>(&W1t[(long)col*256 + kk*32 + lk*8]);
            #pragma unroll
            for (int rt = 0; rt < 4; ++rt)
                acc[rt][ctl] = __builtin_amdgcn_mfma_f32_16x16x32_bf16(av[rt], bv, acc[rt][ctl], 0, 0, 0);
        }
    }
    __syncthreads();
    #pragma unroll
    for (int ctl = 0; ctl < 4; ++ctl) {
        int col = wbase + ctl*16 + lr;
        float b1v = b1[col];
        #pragma unroll
        for (int rt = 0; rt < 4; ++rt) {
            #pragma unroll
            for (int i = 0; i < 4; ++i) {
                int r = rt*16 + lk*4 + i;
                float v = acc[rt][ctl][i] + b1v;
                float g = 0.5f * v * (1.0f + erff(v * 0.70710678118654752f));
                int cchunk = (col >> 3) ^ (r & 7);
                xs[(r*32 + cchunk)*8 + (col & 7)] = f2bf(g);
            }
        }
    }
    __syncthreads();
    f32x4 acc2[4][4];
    #pragma unroll
    for (int rt = 0; rt < 4; ++rt)
        #pragma unroll
        for (int ctl = 0; ctl < 4; ++ctl) acc2[rt][ctl] = zero4;
    #pragma unroll
    for (int kk = 0; kk < 8; ++kk) {
        bf16x8 av[4];
        #pragma unroll
        for (int rt = 0; rt < 4; ++rt) {
            int r = rt*16 + lr;
            int sp = (kk*4 + lk) ^ (r & 7);
            av[rt] = *reinterpret_cast<const bf16x8*>(&xs[(r*32 + sp)*8]);
        }
        #pragma unroll
        for (int ctl = 0; ctl < 4; ++ctl) {
            int col = wbase + ctl*16 + lr;
            bf16x8 bv = *reinterpret_cast<const bf16x8*>(&W2t[(long)col*256 + kk*32 + lk*8]);
            #pragma unroll
            for (int rt = 0; rt < 4; ++rt)
                acc2[rt][ctl] = __builtin_amdgcn_mfma_f32_16x16x32_bf16(av[rt], bv, acc2[rt][ctl], 0, 0, 0);
        }
    }
    int used = used_g[b];
    #pragma unroll
    for (int ctl = 0; ctl < 4; ++ctl) {
        float ps = 0.f;
        #pragma unroll
        for (int rt = 0; rt < 4; ++rt)
            #pragma unroll
            for (int i = 0; i < 4; ++i)
                ps += attn_s[rt*16 + lk*4 + i] * acc2[rt][ctl][i];
        ps += __shfl_xor(ps, 16, 64);
        ps += __shfl_xor(ps, 32, 64);
        if (l < 16) {
            int col = wbase + ctl*16 + l;
            out_sum[b*256 + col] = used ? (ps + b2[col]) : fb_sum[col];
        }
    }
}

extern "C" void kernel_launch(void* const* d_in, const int* in_sizes, int n_in,
                              void* d_out, int out_size, void* d_ws, size_t ws_size,
                              hipStream_t stream) {
    const float* cr   = (const float*)d_in[0];
    const int*   sid  = (const int*)d_in[1];
    const float* item = (const float*)d_in[2];
    const float* fq   = (const float*)d_in[3];
    const int*   sq   = (const int*)d_in[4];
    const int*   tq   = (const int*)d_in[5];
    const float* Wq   = (const float*)d_in[6];
    const float* bq   = (const float*)d_in[7];
    const float* Wk   = (const float*)d_in[8];
    const float* bk   = (const float*)d_in[9];
    const float* W1   = (const float*)d_in[10];
    const float* b1   = (const float*)d_in[11];
    const float* W2   = (const float*)d_in[12];
    const float* b2   = (const float*)d_in[13];
    const float* fbc  = (const float*)d_in[14];
    const float* fbs  = (const float*)d_in[15];

    float* out_ctx  = (float*)d_out;
    float* out_sum  = out_ctx + 1024*128;
    float* out_used = out_sum + 1024*256;

    char* w = (char*)d_ws;
    unsigned short* k_hi = (unsigned short*)w;  w += (size_t)MQ*128*2;
    double* invn = (double*)w;                  w += (size_t)MQ*8;
    double* q64 = (double*)w;                   w += (size_t)1024*128*8;
    unsigned short* qbf = (unsigned short*)w;   w += (size_t)1024*128*2;
    unsigned short* W1t = (unsigned short*)w;   w += (size_t)256*256*2;
    unsigned short* W2t = (unsigned short*)w;   w += (size_t)256*256*2;
    int* cand = (int*)w;                        w += (size_t)1024*CAP*4;
    int* cnt = (int*)w;                         w += (size_t)1024*4;
    float* attn_g = (float*)w;                  w += (size_t)1024*TOPK*4;
    int* tidx_g = (int*)w;                      w += (size_t)1024*TOPK*4;
    int* used_g = (int*)w;                      w += (size_t)1024*4;
    int* rhist = (int*)w;                       w += (size_t)1024*64*4;
    float* Trow = (float*)w;                    w += (size_t)1024*4;

    hipMemsetAsync(cnt, 0, 1024*4, stream);
    hipMemsetAsync(rhist, 0, 1024*64*4, stream);
    k_transpose<<<512, 256, 0, stream>>>(W1, W2, W1t, W2t);
    k_qproj<<<1024, 128, 0, stream>>>(cr, Wq, bq, q64, qbf);
    k_kproj<<<(MQ + 127)/128, 256, 0, stream>>>(fq, Wk, bk, k_hi, invn);
    k_sims_t<true><<<(MQ + 63)/64, 256, 0, stream>>>(qbf, k_hi, rhist, nullptr, nullptr, nullptr);
    k_pick<<<4, 256, 0, stream>>>(rhist, Trow);
    k_sims_t<false><<<(MQ + 63)/64, 256, 0, stream>>>(qbf, k_hi, nullptr, Trow, cnt, cand);
    k_select<<<1024, 256, 0, stream>>>(q64, Wk, bk, fq, invn, sq, sid, cnt, cand,
                                       attn_g, tidx_g, used_g, out_ctx, out_used, fbc);
    k_mlp<<<1024, 256, 0, stream>>>(fq, item, tq, W1t, W2t, b1, b2,
                                    attn_g, tidx_g, used_g, fbs, out_sum);
}

// Round 4
// 754.074 us; speedup vs baseline: 1.1893x; 1.1893x over previous
//
#include <hip/hip_runtime.h>
#include <hip/hip_bf16.h>

#define TOPK 50
#define CAP 512
#define MQ 100000
#define ZCUT 2.9f
#define EPS2 0.006f
#define NS_BLK 49          // stats blocks, 256 samples each, stride 8
#define NS_CNT 12500.0f    // valid samples
#define NAPP ((MQ + 255) / 256)

typedef float f32x4 __attribute__((ext_vector_type(4)));
typedef __bf16 bf16x8 __attribute__((ext_vector_type(8)));
typedef unsigned short u16x8 __attribute__((ext_vector_type(8)));
typedef unsigned short u16x4 __attribute__((ext_vector_type(4)));

__device__ __forceinline__ unsigned short f2bf(float f) {
    unsigned int u = __float_as_uint(f);
    return (unsigned short)((u + 0x7fffu + ((u >> 16) & 1u)) >> 16);
}
__device__ __forceinline__ float bf2f(unsigned short u) {
    return __uint_as_float(((unsigned int)u) << 16);
}

// ---------------- K0: transpose W1/W2 to bf16 [C][K] ----------------
__global__ void k_transpose(const float* __restrict__ W1, const float* __restrict__ W2,
                            unsigned short* __restrict__ W1t, unsigned short* __restrict__ W2t) {
    int c = blockIdx.x & 255;
    int k = threadIdx.x;
    if (blockIdx.x < 256) W1t[c*256 + k] = f2bf(W1[k*256 + c]);
    else                  W2t[c*256 + k] = f2bf(W2[k*256 + c]);
}

// ---------------- K1: q = l2norm(cr@Wq + bq) in f64 ----------------
__global__ void k_qproj(const float* __restrict__ cr, const float* __restrict__ Wq,
                        const float* __restrict__ bq,
                        double* __restrict__ q64, unsigned short* __restrict__ qbf) {
    int row = blockIdx.x, d = threadIdx.x;
    __shared__ double xs[128];
    __shared__ double red[128];
    xs[d] = (double)cr[row*128 + d];
    __syncthreads();
    double s = (double)bq[d];
    #pragma unroll 4
    for (int i = 0; i < 128; ++i) s += xs[i] * (double)Wq[i*128 + d];
    red[d] = s * s;
    __syncthreads();
    for (int off = 64; off > 0; off >>= 1) {
        if (d < off) red[d] += red[d + off];
        __syncthreads();
    }
    double inv = 1.0 / fmax(sqrt(red[0]), 1e-12);
    double qv = s * inv;
    q64[row*128 + d] = qv;
    qbf[row*128 + d] = f2bf((float)qv);
}

// ---------------- K2: k_hi = bf16(l2norm(fq@Wk + bk)), invn f64 ----------------
__global__ __launch_bounds__(256) void k_kproj(const float* __restrict__ fq,
        const float* __restrict__ Wk, const float* __restrict__ bk,
        unsigned short* __restrict__ k_hi, double* __restrict__ invn) {
    __shared__ __align__(16) float wks[128*128];
    __shared__ __align__(16) float fqs[128*129];
    int t = threadIdx.x;
    long row0 = (long)blockIdx.x * 128;
    for (int j = 0; j < 16; ++j) {
        int id4 = t + 256*j;
        float4 v = reinterpret_cast<const float4*>(Wk)[id4];
        *reinterpret_cast<float4*>(&wks[id4*4]) = v;
    }
    for (int j = 0; j < 16; ++j) {
        int id4 = t + 256*j;
        int r = id4 >> 5;
        int c4 = (id4 & 31) << 2;
        float4 v = {0.f, 0.f, 0.f, 0.f};
        if (row0 + r < MQ) v = *reinterpret_cast<const float4*>(&fq[(row0 + r)*128 + c4]);
        fqs[r*129 + c4 + 0] = v.x;
        fqs[r*129 + c4 + 1] = v.y;
        fqs[r*129 + c4 + 2] = v.z;
        fqs[r*129 + c4 + 3] = v.w;
    }
    __syncthreads();
    const int ct = t & 15, rt = t >> 4;
    const int r0 = rt * 8, c0 = ct * 4;
    float acc[8][8];
    #pragma unroll
    for (int a = 0; a < 8; ++a)
        #pragma unroll
        for (int b = 0; b < 8; ++b) acc[a][b] = 0.f;
    #pragma unroll 2
    for (int i = 0; i < 128; ++i) {
        float4 w0 = *reinterpret_cast<const float4*>(&wks[i*128 + c0]);
        float4 w1 = *reinterpret_cast<const float4*>(&wks[i*128 + 64 + c0]);
        float a[8];
        #pragma unroll
        for (int rr = 0; rr < 8; ++rr) a[rr] = fqs[(r0+rr)*129 + i];
        #pragma unroll
        for (int rr = 0; rr < 8; ++rr) {
            acc[rr][0] = fmaf(a[rr], w0.x, acc[rr][0]);
            acc[rr][1] = fmaf(a[rr], w0.y, acc[rr][1]);
            acc[rr][2] = fmaf(a[rr], w0.z, acc[rr][2]);
            acc[rr][3] = fmaf(a[rr], w0.w, acc[rr][3]);
            acc[rr][4] = fmaf(a[rr], w1.x, acc[rr][4]);
            acc[rr][5] = fmaf(a[rr], w1.y, acc[rr][5]);
            acc[rr][6] = fmaf(a[rr], w1.z, acc[rr][6]);
            acc[rr][7] = fmaf(a[rr], w1.w, acc[rr][7]);
        }
    }
    float bkv[8];
    #pragma unroll
    for (int cc = 0; cc < 4; ++cc) { bkv[cc] = bk[c0+cc]; bkv[4+cc] = bk[64+c0+cc]; }
    #pragma unroll
    for (int rr = 0; rr < 8; ++rr)
        #pragma unroll
        for (int cc = 0; cc < 8; ++cc) acc[rr][cc] += bkv[cc];
    __syncthreads();
    double* npart = reinterpret_cast<double*>(fqs);
    #pragma unroll
    for (int rr = 0; rr < 8; ++rr) {
        double pn = 0.0;
        #pragma unroll
        for (int cc = 0; cc < 8; ++cc) pn += (double)acc[rr][cc] * (double)acc[rr][cc];
        npart[(r0+rr)*16 + ct] = pn;
    }
    __syncthreads();
    double* invd = npart + 128*16;
    if (t < 128) {
        double nn = 0.0;
        for (int k2 = 0; k2 < 16; ++k2) nn += npart[t*16 + k2];
        double iv = 1.0 / fmax(sqrt(nn), 1e-12);
        invd[t] = iv;
        if (row0 + t < MQ) invn[row0 + t] = iv;
    }
    __syncthreads();
    #pragma unroll
    for (int rr = 0; rr < 8; ++rr) {
        long row = row0 + r0 + rr;
        if (row < MQ) {
            float iv = (float)invd[r0 + rr];
            u16x4 o0, o1;
            #pragma unroll
            for (int cc = 0; cc < 4; ++cc) {
                o0[cc] = f2bf(acc[rr][cc] * iv);
                o1[cc] = f2bf(acc[rr][4+cc] * iv);
            }
            *reinterpret_cast<u16x4*>(&k_hi[row*128 + c0]) = o0;
            *reinterpret_cast<u16x4*>(&k_hi[row*128 + 64 + c0]) = o1;
        }
    }
}

// ---------------- K3a: sampled per-row moments (stride-8 cols) ----------------
__global__ __launch_bounds__(256) void k_stats(const unsigned short* __restrict__ qbf,
        const unsigned short* __restrict__ k_hi, float* __restrict__ ws_s) {
    __shared__ float lds_s[4][1024][2];   // per-wave row partials, 32 KB
    int t = threadIdx.x;
    int n = blockIdx.x;
    int w = t >> 6, l = t & 63;
    int lr = l & 15, lk = l >> 4;
    for (int i = t; i < 4*1024*2; i += 256) ((float*)lds_s)[i] = 0.f;
    // B-fragments: 4 col-frags x 4 ksteps, held in registers
    bf16x8 bfr[4][4];
    #pragma unroll
    for (int cf = 0; cf < 4; ++cf) {
        long scol = 8L * (n*256 + w*64 + cf*16 + lr);
        #pragma unroll
        for (int kk = 0; kk < 4; ++kk) {
            u16x8 v = {0,0,0,0,0,0,0,0};
            if (scol < MQ) v = *reinterpret_cast<const u16x8*>(&k_hi[scol*128 + kk*32 + lk*8]);
            bfr[cf][kk] = *reinterpret_cast<bf16x8*>(&v);
        }
    }
    __syncthreads();
    for (int rg = 0; rg < 64; ++rg) {
        bf16x8 a[4];
        #pragma unroll
        for (int kk = 0; kk < 4; ++kk)
            a[kk] = *reinterpret_cast<const bf16x8*>(&qbf[(rg*16 + lr)*128 + kk*32 + lk*8]);
        f32x4 acc[4];
        #pragma unroll
        for (int cf = 0; cf < 4; ++cf) {
            acc[cf] = (f32x4){0.f,0.f,0.f,0.f};
            #pragma unroll
            for (int kk = 0; kk < 4; ++kk)
                acc[cf] = __builtin_amdgcn_mfma_f32_16x16x32_bf16(a[kk], bfr[cf][kk], acc[cf], 0, 0, 0);
        }
        #pragma unroll
        for (int i = 0; i < 4; ++i) {
            float s1 = acc[0][i] + acc[1][i] + acc[2][i] + acc[3][i];
            float s2 = acc[0][i]*acc[0][i] + acc[1][i]*acc[1][i]
                     + acc[2][i]*acc[2][i] + acc[3][i]*acc[3][i];
            #pragma unroll
            for (int m = 1; m < 16; m <<= 1) {
                s1 += __shfl_xor(s1, m, 64);
                s2 += __shfl_xor(s2, m, 64);
            }
            if (lr == 0) {
                int row = rg*16 + lk*4 + i;
                lds_s[w][row][0] += s1;
                lds_s[w][row][1] += s2;
            }
        }
    }
    __syncthreads();
    for (int r = t; r < 1024; r += 256) {
        float a = lds_s[0][r][0] + lds_s[1][r][0] + lds_s[2][r][0] + lds_s[3][r][0];
        float b = lds_s[0][r][1] + lds_s[1][r][1] + lds_s[2][r][1] + lds_s[3][r][1];
        ws_s[n*2048 + r*2 + 0] = a;
        ws_s[n*2048 + r*2 + 1] = b;
    }
}

// ---------------- K3b: per-row threshold from moments ----------------
__global__ void k_thresh(const float* __restrict__ ws_s, float* __restrict__ Trow) {
    int r = blockIdx.x * 256 + threadIdx.x;
    if (r >= 1024) return;
    float s1 = 0.f, s2 = 0.f;
    for (int n = 0; n < NS_BLK; ++n) {
        s1 += ws_s[n*2048 + r*2 + 0];
        s2 += ws_s[n*2048 + r*2 + 1];
    }
    float mu = s1 / NS_CNT;
    float var = s2 / NS_CNT - mu*mu;
    float sg = sqrtf(fmaxf(var, 1e-12f));
    Trow[r] = mu + ZCUT * sg;
}

// ---------------- K3c: append pass — bf16 MFMA sims vs per-row T ----------------
__global__ __launch_bounds__(256) void k_append(const unsigned short* __restrict__ qbf,
        const unsigned short* __restrict__ k_hi, const float* __restrict__ Trow,
        const int* __restrict__ sq, const int* __restrict__ sid,
        int* __restrict__ cnt, int* __restrict__ cnthi, int* __restrict__ cand) {
    int t = threadIdx.x;
    int col0 = blockIdx.x * 256;
    int w = t >> 6, l = t & 63;
    int lr = l & 15, lk = l >> 4;
    // B-fragments in registers: 4 col-frags x 4 ksteps
    bf16x8 bfr[4][4];
    int colg[4];
    #pragma unroll
    for (int cf = 0; cf < 4; ++cf) {
        long c = col0 + w*64 + cf*16 + lr;
        colg[cf] = (int)c;
        #pragma unroll
        for (int kk = 0; kk < 4; ++kk) {
            u16x8 v = {0,0,0,0,0,0,0,0};
            if (c < MQ) v = *reinterpret_cast<const u16x8*>(&k_hi[c*128 + kk*32 + lk*8]);
            bfr[cf][kk] = *reinterpret_cast<bf16x8*>(&v);
        }
    }
    for (int rg = 0; rg < 64; ++rg) {
        bf16x8 a[4];
        #pragma unroll
        for (int kk = 0; kk < 4; ++kk)
            a[kk] = *reinterpret_cast<const bf16x8*>(&qbf[(rg*16 + lr)*128 + kk*32 + lk*8]);
        f32x4 T4 = *reinterpret_cast<const f32x4*>(&Trow[rg*16 + lk*4]);
        float Tmin = fminf(fminf(T4[0], T4[1]), fminf(T4[2], T4[3]));
        f32x4 acc[4];
        #pragma unroll
        for (int cf = 0; cf < 4; ++cf) {
            acc[cf] = (f32x4){0.f,0.f,0.f,0.f};
            #pragma unroll
            for (int kk = 0; kk < 4; ++kk)
                acc[cf] = __builtin_amdgcn_mfma_f32_16x16x32_bf16(a[kk], bfr[cf][kk], acc[cf], 0, 0, 0);
        }
        #pragma unroll
        for (int cf = 0; cf < 4; ++cf) {
            float mx = fmaxf(fmaxf(acc[cf][0], acc[cf][1]), fmaxf(acc[cf][2], acc[cf][3]));
            if (mx >= Tmin && colg[cf] < MQ) {
                #pragma unroll
                for (int i = 0; i < 4; ++i) {
                    float v = acc[cf][i];
                    if (v >= T4[i]) {
                        int r = rg*16 + lk*4 + i;
                        int pos = atomicAdd(&cnt[r], 1);
                        if (pos < CAP) cand[r*CAP + pos] = colg[cf];
                        if (v >= T4[i] + EPS2 && sq[colg[cf]] != sid[r])
                            atomicAdd(&cnthi[r], 1);
                    }
                }
            }
        }
    }
}

// ---------------- K3d: fallback — exact per-row redo for flagged rows ----------------
__global__ __launch_bounds__(256) void k_fix(const unsigned short* __restrict__ qbf,
        const unsigned short* __restrict__ k_hi,
        const int* __restrict__ sq, const int* __restrict__ sid,
        int* __restrict__ cnt, const int* __restrict__ cnthi, int* __restrict__ cand) {
    int row = blockIdx.x;
    if (cnthi[row] >= TOPK && cnt[row] <= CAP) return;
    __shared__ float qr[128];
    __shared__ int hist[1024];
    __shared__ float Tsh;
    int t = threadIdx.x;
    if (t < 128) qr[t] = bf2f(qbf[row*128 + t]);
    for (int i = t; i < 1024; i += 256) hist[i] = 0;
    __syncthreads();
    int myses = sid[row];
    for (int c = t; c < MQ; c += 256) {
        if (sq[c] == myses) continue;
        const u16x8* kr = reinterpret_cast<const u16x8*>(k_hi + (long)c*128);
        float v = 0.f;
        for (int j = 0; j < 16; ++j) {
            u16x8 kv = kr[j];
            #pragma unroll
            for (int e = 0; e < 8; ++e) v += qr[j*8+e] * bf2f(kv[e]);
        }
        int b = (int)((v + 1.0f) * 512.0f);
        b = b < 0 ? 0 : (b > 1023 ? 1023 : b);
        atomicAdd(&hist[b], 1);
    }
    __syncthreads();
    if (t == 0) {
        int cum = 0; float T = -2.0f;
        for (int b = 1023; b >= 0; --b) {
            cum += hist[b];
            if (cum >= TOPK) { T = (float)b * (1.0f/512.0f) - 1.0f - 0.005f; break; }
        }
        Tsh = T;
        cnt[row] = 0;
    }
    __syncthreads();
    float T = Tsh;
    for (int c = t; c < MQ; c += 256) {
        const u16x8* kr = reinterpret_cast<const u16x8*>(k_hi + (long)c*128);
        float v = 0.f;
        for (int j = 0; j < 16; ++j) {
            u16x8 kv = kr[j];
            #pragma unroll
            for (int e = 0; e < 8; ++e) v += qr[j*8+e] * bf2f(kv[e]);
        }
        if (v >= T) {
            int pos = atomicAdd(&cnt[row], 1);
            if (pos < CAP) cand[row*CAP + pos] = c;
        }
    }
}

// ---------------- K4: exact f64 re-score, top-50, softmax, context ----------------
__global__ __launch_bounds__(256) void k_select(
        const double* __restrict__ q64, const float* __restrict__ Wk,
        const float* __restrict__ bk, const float* __restrict__ fq,
        const double* __restrict__ invn, const int* __restrict__ sq,
        const int* __restrict__ sid, const int* __restrict__ cnt,
        const int* __restrict__ cand,
        float* __restrict__ attn_g, int* __restrict__ tidx_g, int* __restrict__ used_g,
        float* __restrict__ out_ctx, float* __restrict__ out_used,
        const float* __restrict__ fb_ctx) {
    __shared__ double qs[128];
    __shared__ double wqr[128];
    __shared__ double qb_s;
    __shared__ double vals[CAP];
    __shared__ int cidx[CAP];
    __shared__ double selv[TOPK];
    __shared__ int seli[TOPK];
    __shared__ float attn_s[TOPK];
    __shared__ int used_s;
    int row = blockIdx.x, t = threadIdx.x;
    if (t < 128) qs[t] = q64[row*128 + t];
    __syncthreads();
    if (t < 128) {
        double s = 0.0;
        for (int d = 0; d < 128; ++d) s += (double)Wk[t*128 + d] * qs[d];
        wqr[t] = s;
    }
    if (t == 0) {
        double s = 0.0;
        for (int d = 0; d < 128; ++d) s += qs[d] * (double)bk[d];
        qb_s = s;
    }
    if (t < TOPK) { selv[t] = -1e290; seli[t] = 0; }
    __syncthreads();
    int n = cnt[row]; if (n > CAP) n = CAP;
    int myses = sid[row];
    for (int j = t; j < n; j += 256) {
        int c = cand[row*CAP + j];
        cidx[j] = c;
        double v;
        if (sq[c] == myses) v = -1e300;
        else {
            double s = qb_s;
            const float4* xr4 = reinterpret_cast<const float4*>(fq + (long)c*128);
            for (int i4 = 0; i4 < 32; ++i4) {
                float4 x4 = xr4[i4];
                s += (double)x4.x * wqr[i4*4+0] + (double)x4.y * wqr[i4*4+1]
                   + (double)x4.z * wqr[i4*4+2] + (double)x4.w * wqr[i4*4+3];
            }
            v = s * invn[c];
        }
        vals[j] = v;
    }
    __syncthreads();
    for (int j = t; j < n; j += 256) {
        double v = vals[j]; int ci = cidx[j];
        int rk = 0;
        for (int m2 = 0; m2 < n; ++m2) {
            double vm = vals[m2];
            rk += (vm > v) || (vm == v && cidx[m2] < ci);
        }
        if (rk < TOPK) { selv[rk] = v; seli[rk] = ci; }
    }
    __syncthreads();
    if (t == 0) {
        double vmax = -1.0e308;
        for (int r = 0; r < TOPK; ++r)
            if (selv[r] > -1e250 && selv[r] > vmax) vmax = selv[r];
        float ssum = 0.f;
        for (int r = 0; r < TOPK; ++r) {
            float ev = 0.f;
            if (selv[r] > -1e250) ev = expf((float)((selv[r] - vmax) * (1.0/0.07)));
            attn_s[r] = ev; ssum += ev;
        }
        float invs = (ssum > 0.f) ? 1.0f/ssum : 0.0f;
        for (int r = 0; r < TOPK; ++r) attn_s[r] *= invs;
        used_s = (ssum > 0.f) ? 1 : 0;
        used_g[row] = used_s;
    }
    __syncthreads();
    int used = used_s;
    if (t < TOPK) { attn_g[row*TOPK + t] = attn_s[t]; tidx_g[row*TOPK + t] = seli[t]; }
    if (t < 128) {
        float cacc = 0.f;
        for (int r = 0; r < TOPK; ++r) cacc += attn_s[r] * fq[(long)seli[r]*128 + t];
        out_ctx[row*128 + t] = used ? cacc : fb_ctx[t];
    }
    if (t == 0) out_used[row] = used ? 1.0f : 0.0f;
}

// ---------------- K5: fused MLP ----------------
__global__ __launch_bounds__(256) void k_mlp(
        const float* __restrict__ fq, const float* __restrict__ item_emb,
        const int* __restrict__ tq,
        const unsigned short* __restrict__ W1t, const unsigned short* __restrict__ W2t,
        const float* __restrict__ b1, const float* __restrict__ b2,
        const float* __restrict__ attn_g, const int* __restrict__ tidx_g,
        const int* __restrict__ used_g,
        const float* __restrict__ fb_sum, float* __restrict__ out_sum) {
    __shared__ __align__(16) unsigned short xs[64*256];
    __shared__ float attn_s[64];
    __shared__ int tgt_s[64];
    __shared__ int tix_s[64];
    int b = blockIdx.x, t = threadIdx.x;
    if (t < 64) {
        float a = 0.f; int ti = 0;
        if (t < TOPK) { a = attn_g[b*TOPK + t]; ti = tidx_g[b*TOPK + t]; }
        attn_s[t] = a; tix_s[t] = ti;
        int tg = 0;
        if (t < TOPK) { tg = tq[ti]; if (tg < 0) tg = 0; }
        tgt_s[t] = tg;
    }
    __syncthreads();
    for (int j = 0; j < 8; ++j) {
        int chunk = t + 256*j;
        int r = chunk >> 5, s = chunk & 31;
        int sp = s ^ (r & 7);
        u16x8 o = {0,0,0,0,0,0,0,0};
        if (r < TOPK) {
            int c0 = s * 8;
            const float* src = (c0 < 128) ? (fq + (long)tix_s[r]*128 + c0)
                                          : (item_emb + (long)tgt_s[r]*128 + (c0 - 128));
            float4 v0 = *reinterpret_cast<const float4*>(src);
            float4 v1 = *reinterpret_cast<const float4*>(src + 4);
            o[0] = f2bf(v0.x); o[1] = f2bf(v0.y); o[2] = f2bf(v0.z); o[3] = f2bf(v0.w);
            o[4] = f2bf(v1.x); o[5] = f2bf(v1.y); o[6] = f2bf(v1.z); o[7] = f2bf(v1.w);
        }
        *reinterpret_cast<u16x8*>(&xs[(r*32 + sp)*8]) = o;
    }
    __syncthreads();
    int w = t >> 6, l = t & 63, lr = l & 15, lk = l >> 4;
    int wbase = w * 64;
    f32x4 zero4 = {0.f, 0.f, 0.f, 0.f};
    f32x4 acc[4][4];
    #pragma unroll
    for (int rt = 0; rt < 4; ++rt)
        #pragma unroll
        for (int ctl = 0; ctl < 4; ++ctl) acc[rt][ctl] = zero4;
    #pragma unroll
    for (int kk = 0; kk < 8; ++kk) {
        bf16x8 av[4];
        #pragma unroll
        for (int rt = 0; rt < 4; ++rt) {
            int r = rt*16 + lr;
            int sp = (kk*4 + lk) ^ (r & 7);
            av[rt] = *reinterpret_cast<const bf16x8*>(&xs[(r*32 + sp)*8]);
        }
        #pragma unroll
        for (int ctl = 0; ctl < 4; ++ctl) {
            int col = wbase + ctl*16 + lr;
            bf16x8 bv = *reinterpret_cast<const bf16x8*>(&W1t[(long)col*256 + kk*32 + lk*8]);
            #pragma unroll
            for (int rt = 0; rt < 4; ++rt)
                acc[rt][ctl] = __builtin_amdgcn_mfma_f32_16x16x32_bf16(av[rt], bv, acc[rt][ctl], 0, 0, 0);
        }
    }
    __syncthreads();
    #pragma unroll
    for (int ctl = 0; ctl < 4; ++ctl) {
        int col = wbase + ctl*16 + lr;
        float b1v = b1[col];
        #pragma unroll
        for (int rt = 0; rt < 4; ++rt) {
            #pragma unroll
            for (int i = 0; i < 4; ++i) {
                int r = rt*16 + lk*4 + i;
                float v = acc[rt][ctl][i] + b1v;
                float g = 0.5f * v * (1.0f + erff(v * 0.70710678118654752f));
                int cchunk = (col >> 3) ^ (r & 7);
                xs[(r*32 + cchunk)*8 + (col & 7)] = f2bf(g);
            }
        }
    }
    __syncthreads();
    f32x4 acc2[4][4];
    #pragma unroll
    for (int rt = 0; rt < 4; ++rt)
        #pragma unroll
        for (int ctl = 0; ctl < 4; ++ctl) acc2[rt][ctl] = zero4;
    #pragma unroll
    for (int kk = 0; kk < 8; ++kk) {
        bf16x8 av[4];
        #pragma unroll
        for (int rt = 0; rt < 4; ++rt) {
            int r = rt*16 + lr;
            int sp = (kk*4 + lk) ^ (r & 7);
            av[rt] = *reinterpret_cast<const bf16x8*>(&xs[(r*32 + sp)*8]);
        }
        #pragma unroll
        for (int ctl = 0; ctl < 4; ++ctl) {
            int col = wbase + ctl*16 + lr;
            bf16x8 bv = *reinterpret_cast<const bf16x8*>(&W2t[(long)col*256 + kk*32 + lk*8]);
            #pragma unroll
            for (int rt = 0; rt < 4; ++rt)
                acc2[rt][ctl] = __builtin_amdgcn_mfma_f32_16x16x32_bf16(av[rt], bv, acc2[rt][ctl], 0, 0, 0);
        }
    }
    int used = used_g[b];
    #pragma unroll
    for (int ctl = 0; ctl < 4; ++ctl) {
        float ps = 0.f;
        #pragma unroll
        for (int rt = 0; rt < 4; ++rt)
            #pragma unroll
            for (int i = 0; i < 4; ++i)
                ps += attn_s[rt*16 + lk*4 + i] * acc2[rt][ctl][i];
        ps += __shfl_xor(ps, 16, 64);
        ps += __shfl_xor(ps, 32, 64);
        if (l < 16) {
            int col = wbase + ctl*16 + l;
            out_sum[b*256 + col] = used ? (ps + b2[col]) : fb_sum[col];
        }
    }
}

extern "C" void kernel_launch(void* const* d_in, const int* in_sizes, int n_in,
                              void* d_out, int out_size, void* d_ws, size_t ws_size,
                              hipStream_t stream) {
    const float* cr   = (const float*)d_in[0];
    const int*   sid  = (const int*)d_in[1];
    const float* item = (const float*)d_in[2];
    const float* fq   = (const float*)d_in[3];
    const int*   sq   = (const int*)d_in[4];
    const int*   tq   = (const int*)d_in[5];
    const float* Wq   = (const float*)d_in[6];
    const float* bq   = (const float*)d_in[7];
    const float* Wk   = (const float*)d_in[8];
    const float* bk   = (const float*)d_in[9];
    const float* W1   = (const float*)d_in[10];
    const float* b1   = (const float*)d_in[11];
    const float* W2   = (const float*)d_in[12];
    const float* b2   = (const float*)d_in[13];
    const float* fbc  = (const float*)d_in[14];
    const float* fbs  = (const float*)d_in[15];

    float* out_ctx  = (float*)d_out;
    float* out_sum  = out_ctx + 1024*128;
    float* out_used = out_sum + 1024*256;

    char* w = (char*)d_ws;
    unsigned short* k_hi = (unsigned short*)w;  w += (size_t)MQ*128*2;
    double* invn = (double*)w;                  w += (size_t)MQ*8;
    double* q64 = (double*)w;                   w += (size_t)1024*128*8;
    unsigned short* qbf = (unsigned short*)w;   w += (size_t)1024*128*2;
    unsigned short* W1t = (unsigned short*)w;   w += (size_t)256*256*2;
    unsigned short* W2t = (unsigned short*)w;   w += (size_t)256*256*2;
    int* cand = (int*)w;                        w += (size_t)1024*CAP*4;
    int* cnt = (int*)w;                         w += (size_t)1024*4;
    int* cnthi = (int*)w;                       w += (size_t)1024*4;
    float* attn_g = (float*)w;                  w += (size_t)1024*TOPK*4;
    int* tidx_g = (int*)w;                      w += (size_t)1024*TOPK*4;
    int* used_g = (int*)w;                      w += (size_t)1024*4;
    float* ws_s = (float*)w;                    w += (size_t)NS_BLK*2048*4;
    float* Trow = (float*)w;                    w += (size_t)1024*4;

    hipMemsetAsync(cnt, 0, 1024*4, stream);
    hipMemsetAsync(cnthi, 0, 1024*4, stream);
    k_transpose<<<512, 256, 0, stream>>>(W1, W2, W1t, W2t);
    k_qproj<<<1024, 128, 0, stream>>>(cr, Wq, bq, q64, qbf);
    k_kproj<<<(MQ + 127)/128, 256, 0, stream>>>(fq, Wk, bk, k_hi, invn);
    k_stats<<<NS_BLK, 256, 0, stream>>>(qbf, k_hi, ws_s);
    k_thresh<<<4, 256, 0, stream>>>(ws_s, Trow);
    k_append<<<NAPP, 256, 0, stream>>>(qbf, k_hi, Trow, sq, sid, cnt, cnthi, cand);
    k_fix<<<1024, 256, 0, stream>>>(qbf, k_hi, sq, sid, cnt, cnthi, cand);
    k_select<<<1024, 256, 0, stream>>>(q64, Wk, bk, fq, invn, sq, sid, cnt, cand,
                                       attn_g, tidx_g, used_g, out_ctx, out_used, fbc);
    k_mlp<<<1024, 256, 0, stream>>>(fq, item, tq, W1t, W2t, b1, b2,
                                    attn_g, tidx_g, used_g, fbs, out_sum);
}

// Round 5
// 733.087 us; speedup vs baseline: 1.2234x; 1.0286x over previous
//
#include <hip/hip_runtime.h>
#include <hip/hip_bf16.h>

#define TOPK 50
#define CAP 512
#define MQ 100000
#define ZCUT 2.9f
#define EPS2 0.006f
#define NS_BLK 49          // stats col-chunks, 256 samples each, stride 8
#define NS_CNT 12500.0f    // valid samples
#define NAPP ((MQ + 255) / 256)

typedef float f32x4 __attribute__((ext_vector_type(4)));
typedef __bf16 bf16x8 __attribute__((ext_vector_type(8)));
typedef unsigned short u16x8 __attribute__((ext_vector_type(8)));
typedef unsigned short u16x4 __attribute__((ext_vector_type(4)));

__device__ __forceinline__ unsigned short f2bf(float f) {
    unsigned int u = __float_as_uint(f);
    return (unsigned short)((u + 0x7fffu + ((u >> 16) & 1u)) >> 16);
}
__device__ __forceinline__ float bf2f(unsigned short u) {
    return __uint_as_float(((unsigned int)u) << 16);
}

// ---------------- K0: transpose W1/W2 to bf16 [C][K] ----------------
__global__ void k_transpose(const float* __restrict__ W1, const float* __restrict__ W2,
                            unsigned short* __restrict__ W1t, unsigned short* __restrict__ W2t) {
    int c = blockIdx.x & 255;
    int k = threadIdx.x;
    if (blockIdx.x < 256) W1t[c*256 + k] = f2bf(W1[k*256 + c]);
    else                  W2t[c*256 + k] = f2bf(W2[k*256 + c]);
}

// ---------------- K1: q = l2norm(cr@Wq + bq) in f64 ----------------
__global__ void k_qproj(const float* __restrict__ cr, const float* __restrict__ Wq,
                        const float* __restrict__ bq,
                        double* __restrict__ q64, unsigned short* __restrict__ qbf) {
    int row = blockIdx.x, d = threadIdx.x;
    __shared__ double xs[128];
    __shared__ double red[128];
    xs[d] = (double)cr[row*128 + d];
    __syncthreads();
    double s = (double)bq[d];
    #pragma unroll 4
    for (int i = 0; i < 128; ++i) s += xs[i] * (double)Wq[i*128 + d];
    red[d] = s * s;
    __syncthreads();
    for (int off = 64; off > 0; off >>= 1) {
        if (d < off) red[d] += red[d + off];
        __syncthreads();
    }
    double inv = 1.0 / fmax(sqrt(red[0]), 1e-12);
    double qv = s * inv;
    q64[row*128 + d] = qv;
    qbf[row*128 + d] = f2bf((float)qv);
}

// ---------------- K2: k_hi = bf16(l2norm(fq@Wk + bk)), invn f64 ----------------
__global__ __launch_bounds__(256) void k_kproj(const float* __restrict__ fq,
        const float* __restrict__ Wk, const float* __restrict__ bk,
        unsigned short* __restrict__ k_hi, double* __restrict__ invn) {
    __shared__ __align__(16) float wks[128*128];
    __shared__ __align__(16) float fqs[128*129];
    int t = threadIdx.x;
    long row0 = (long)blockIdx.x * 128;
    for (int j = 0; j < 16; ++j) {
        int id4 = t + 256*j;
        float4 v = reinterpret_cast<const float4*>(Wk)[id4];
        *reinterpret_cast<float4*>(&wks[id4*4]) = v;
    }
    for (int j = 0; j < 16; ++j) {
        int id4 = t + 256*j;
        int r = id4 >> 5;
        int c4 = (id4 & 31) << 2;
        float4 v = {0.f, 0.f, 0.f, 0.f};
        if (row0 + r < MQ) v = *reinterpret_cast<const float4*>(&fq[(row0 + r)*128 + c4]);
        fqs[r*129 + c4 + 0] = v.x;
        fqs[r*129 + c4 + 1] = v.y;
        fqs[r*129 + c4 + 2] = v.z;
        fqs[r*129 + c4 + 3] = v.w;
    }
    __syncthreads();
    const int ct = t & 15, rt = t >> 4;
    const int r0 = rt * 8, c0 = ct * 4;
    float acc[8][8];
    #pragma unroll
    for (int a = 0; a < 8; ++a)
        #pragma unroll
        for (int b = 0; b < 8; ++b) acc[a][b] = 0.f;
    #pragma unroll 2
    for (int i = 0; i < 128; ++i) {
        float4 w0 = *reinterpret_cast<const float4*>(&wks[i*128 + c0]);
        float4 w1 = *reinterpret_cast<const float4*>(&wks[i*128 + 64 + c0]);
        float a[8];
        #pragma unroll
        for (int rr = 0; rr < 8; ++rr) a[rr] = fqs[(r0+rr)*129 + i];
        #pragma unroll
        for (int rr = 0; rr < 8; ++rr) {
            acc[rr][0] = fmaf(a[rr], w0.x, acc[rr][0]);
            acc[rr][1] = fmaf(a[rr], w0.y, acc[rr][1]);
            acc[rr][2] = fmaf(a[rr], w0.z, acc[rr][2]);
            acc[rr][3] = fmaf(a[rr], w0.w, acc[rr][3]);
            acc[rr][4] = fmaf(a[rr], w1.x, acc[rr][4]);
            acc[rr][5] = fmaf(a[rr], w1.y, acc[rr][5]);
            acc[rr][6] = fmaf(a[rr], w1.z, acc[rr][6]);
            acc[rr][7] = fmaf(a[rr], w1.w, acc[rr][7]);
        }
    }
    float bkv[8];
    #pragma unroll
    for (int cc = 0; cc < 4; ++cc) { bkv[cc] = bk[c0+cc]; bkv[4+cc] = bk[64+c0+cc]; }
    #pragma unroll
    for (int rr = 0; rr < 8; ++rr)
        #pragma unroll
        for (int cc = 0; cc < 8; ++cc) acc[rr][cc] += bkv[cc];
    __syncthreads();
    double* npart = reinterpret_cast<double*>(fqs);
    #pragma unroll
    for (int rr = 0; rr < 8; ++rr) {
        double pn = 0.0;
        #pragma unroll
        for (int cc = 0; cc < 8; ++cc) pn += (double)acc[rr][cc] * (double)acc[rr][cc];
        npart[(r0+rr)*16 + ct] = pn;
    }
    __syncthreads();
    double* invd = npart + 128*16;
    if (t < 128) {
        double nn = 0.0;
        for (int k2 = 0; k2 < 16; ++k2) nn += npart[t*16 + k2];
        double iv = 1.0 / fmax(sqrt(nn), 1e-12);
        invd[t] = iv;
        if (row0 + t < MQ) invn[row0 + t] = iv;
    }
    __syncthreads();
    #pragma unroll
    for (int rr = 0; rr < 8; ++rr) {
        long row = row0 + r0 + rr;
        if (row < MQ) {
            float iv = (float)invd[r0 + rr];
            u16x4 o0, o1;
            #pragma unroll
            for (int cc = 0; cc < 4; ++cc) {
                o0[cc] = f2bf(acc[rr][cc] * iv);
                o1[cc] = f2bf(acc[rr][4+cc] * iv);
            }
            *reinterpret_cast<u16x4*>(&k_hi[row*128 + c0]) = o0;
            *reinterpret_cast<u16x4*>(&k_hi[row*128 + 64 + c0]) = o1;
        }
    }
}

// ---------------- K3a: sampled per-row moments (stride-8 cols) ----------------
// grid (NS_BLK, 8): blockIdx.x = col chunk, blockIdx.y = row chunk (8 rg = 128 rows)
__global__ __launch_bounds__(256) void k_stats(const unsigned short* __restrict__ qbf,
        const unsigned short* __restrict__ k_hi, float* __restrict__ ws_s) {
    __shared__ float lds_s[4][128][2];   // per-wave row partials, 4 KB
    int t = threadIdx.x;
    int n = blockIdx.x;
    int rc = blockIdx.y;
    int w = t >> 6, l = t & 63;
    int lr = l & 15, lk = l >> 4;
    for (int i = t; i < 4*128*2; i += 256) ((float*)lds_s)[i] = 0.f;
    // B-fragments: 4 col-frags x 4 ksteps, held in registers
    bf16x8 bfr[4][4];
    #pragma unroll
    for (int cf = 0; cf < 4; ++cf) {
        long scol = 8L * (n*256 + w*64 + cf*16 + lr);
        #pragma unroll
        for (int kk = 0; kk < 4; ++kk) {
            u16x8 v = {0,0,0,0,0,0,0,0};
            if (scol < MQ) v = *reinterpret_cast<const u16x8*>(&k_hi[scol*128 + kk*32 + lk*8]);
            bfr[cf][kk] = *reinterpret_cast<bf16x8*>(&v);
        }
    }
    __syncthreads();
    int rg0 = rc * 8;
    bf16x8 a_nxt[4];
    #pragma unroll
    for (int kk = 0; kk < 4; ++kk)
        a_nxt[kk] = *reinterpret_cast<const bf16x8*>(&qbf[(rg0*16 + lr)*128 + kk*32 + lk*8]);
    for (int j = 0; j < 8; ++j) {
        bf16x8 a[4];
        #pragma unroll
        for (int kk = 0; kk < 4; ++kk) a[kk] = a_nxt[kk];
        if (j < 7) {
            #pragma unroll
            for (int kk = 0; kk < 4; ++kk)
                a_nxt[kk] = *reinterpret_cast<const bf16x8*>(&qbf[((rg0+j+1)*16 + lr)*128 + kk*32 + lk*8]);
        }
        f32x4 acc[4];
        #pragma unroll
        for (int cf = 0; cf < 4; ++cf) {
            acc[cf] = (f32x4){0.f,0.f,0.f,0.f};
            #pragma unroll
            for (int kk = 0; kk < 4; ++kk)
                acc[cf] = __builtin_amdgcn_mfma_f32_16x16x32_bf16(a[kk], bfr[cf][kk], acc[cf], 0, 0, 0);
        }
        #pragma unroll
        for (int i = 0; i < 4; ++i) {
            float s1 = acc[0][i] + acc[1][i] + acc[2][i] + acc[3][i];
            float s2 = acc[0][i]*acc[0][i] + acc[1][i]*acc[1][i]
                     + acc[2][i]*acc[2][i] + acc[3][i]*acc[3][i];
            #pragma unroll
            for (int m = 1; m < 16; m <<= 1) {
                s1 += __shfl_xor(s1, m, 64);
                s2 += __shfl_xor(s2, m, 64);
            }
            if (lr == 0) {
                int rloc = j*16 + lk*4 + i;
                lds_s[w][rloc][0] += s1;
                lds_s[w][rloc][1] += s2;
            }
        }
    }
    __syncthreads();
    int p = n*8 + rc;
    for (int r = t; r < 128; r += 256) {
        float a = lds_s[0][r][0] + lds_s[1][r][0] + lds_s[2][r][0] + lds_s[3][r][0];
        float b = lds_s[0][r][1] + lds_s[1][r][1] + lds_s[2][r][1] + lds_s[3][r][1];
        ws_s[p*256 + r*2 + 0] = a;
        ws_s[p*256 + r*2 + 1] = b;
    }
}

// ---------------- K3b: per-row threshold from moments ----------------
__global__ void k_thresh(const float* __restrict__ ws_s, float* __restrict__ Trow) {
    int r = blockIdx.x * 256 + threadIdx.x;
    if (r >= 1024) return;
    int rc = r >> 7, rl = r & 127;
    float s1 = 0.f, s2 = 0.f;
    for (int n = 0; n < NS_BLK; ++n) {
        s1 += ws_s[(n*8 + rc)*256 + rl*2 + 0];
        s2 += ws_s[(n*8 + rc)*256 + rl*2 + 1];
    }
    float mu = s1 / NS_CNT;
    float var = s2 / NS_CNT - mu*mu;
    float sg = sqrtf(fmaxf(var, 1e-12f));
    Trow[r] = mu + ZCUT * sg;
}

// ---------------- K3c: append pass — bf16 MFMA sims vs per-row T ----------------
// grid (NAPP, 4): blockIdx.x = col chunk (256 cols), blockIdx.y = row chunk (16 rg)
__global__ __launch_bounds__(256) void k_append(const unsigned short* __restrict__ qbf,
        const unsigned short* __restrict__ k_hi, const float* __restrict__ Trow,
        const int* __restrict__ sq, const int* __restrict__ sid,
        int* __restrict__ cnt, int* __restrict__ cnthi, int* __restrict__ cand) {
    int t = threadIdx.x;
    int col0 = blockIdx.x * 256;
    int rbase = blockIdx.y * 16;
    int w = t >> 6, l = t & 63;
    int lr = l & 15, lk = l >> 4;
    // B-fragments in registers: 4 col-frags x 4 ksteps
    bf16x8 bfr[4][4];
    int colg[4];
    #pragma unroll
    for (int cf = 0; cf < 4; ++cf) {
        long c = col0 + w*64 + cf*16 + lr;
        colg[cf] = (int)c;
        #pragma unroll
        for (int kk = 0; kk < 4; ++kk) {
            u16x8 v = {0,0,0,0,0,0,0,0};
            if (c < MQ) v = *reinterpret_cast<const u16x8*>(&k_hi[c*128 + kk*32 + lk*8]);
            bfr[cf][kk] = *reinterpret_cast<bf16x8*>(&v);
        }
    }
    bf16x8 a_nxt[4];
    #pragma unroll
    for (int kk = 0; kk < 4; ++kk)
        a_nxt[kk] = *reinterpret_cast<const bf16x8*>(&qbf[(rbase*16 + lr)*128 + kk*32 + lk*8]);
    for (int j = 0; j < 16; ++j) {
        int rg = rbase + j;
        bf16x8 a[4];
        #pragma unroll
        for (int kk = 0; kk < 4; ++kk) a[kk] = a_nxt[kk];
        if (j < 15) {
            #pragma unroll
            for (int kk = 0; kk < 4; ++kk)
                a_nxt[kk] = *reinterpret_cast<const bf16x8*>(&qbf[((rg+1)*16 + lr)*128 + kk*32 + lk*8]);
        }
        f32x4 T4 = *reinterpret_cast<const f32x4*>(&Trow[rg*16 + lk*4]);
        float Tmin = fminf(fminf(T4[0], T4[1]), fminf(T4[2], T4[3]));
        f32x4 acc[4];
        #pragma unroll
        for (int cf = 0; cf < 4; ++cf) {
            acc[cf] = (f32x4){0.f,0.f,0.f,0.f};
            #pragma unroll
            for (int kk = 0; kk < 4; ++kk)
                acc[cf] = __builtin_amdgcn_mfma_f32_16x16x32_bf16(a[kk], bfr[cf][kk], acc[cf], 0, 0, 0);
        }
        #pragma unroll
        for (int cf = 0; cf < 4; ++cf) {
            float mx = fmaxf(fmaxf(acc[cf][0], acc[cf][1]), fmaxf(acc[cf][2], acc[cf][3]));
            if (mx >= Tmin && colg[cf] < MQ) {
                #pragma unroll
                for (int i = 0; i < 4; ++i) {
                    float v = acc[cf][i];
                    if (v >= T4[i]) {
                        int r = rg*16 + lk*4 + i;
                        int pos = atomicAdd(&cnt[r], 1);
                        if (pos < CAP) cand[r*CAP + pos] = colg[cf];
                        if (v >= T4[i] + EPS2 && sq[colg[cf]] != sid[r])
                            atomicAdd(&cnthi[r], 1);
                    }
                }
            }
        }
    }
}

// ---------------- K3d: fallback — exact per-row redo for flagged rows ----------------
__global__ __launch_bounds__(256) void k_fix(const unsigned short* __restrict__ qbf,
        const unsigned short* __restrict__ k_hi,
        const int* __restrict__ sq, const int* __restrict__ sid,
        int* __restrict__ cnt, const int* __restrict__ cnthi, int* __restrict__ cand) {
    int row = blockIdx.x;
    if (cnthi[row] >= TOPK && cnt[row] <= CAP) return;
    __shared__ float qr[128];
    __shared__ int hist[1024];
    __shared__ float Tsh;
    int t = threadIdx.x;
    if (t < 128) qr[t] = bf2f(qbf[row*128 + t]);
    for (int i = t; i < 1024; i += 256) hist[i] = 0;
    __syncthreads();
    int myses = sid[row];
    for (int c = t; c < MQ; c += 256) {
        if (sq[c] == myses) continue;
        const u16x8* kr = reinterpret_cast<const u16x8*>(k_hi + (long)c*128);
        float v = 0.f;
        for (int j = 0; j < 16; ++j) {
            u16x8 kv = kr[j];
            #pragma unroll
            for (int e = 0; e < 8; ++e) v += qr[j*8+e] * bf2f(kv[e]);
        }
        int b = (int)((v + 1.0f) * 512.0f);
        b = b < 0 ? 0 : (b > 1023 ? 1023 : b);
        atomicAdd(&hist[b], 1);
    }
    __syncthreads();
    if (t == 0) {
        int cum = 0; float T = -2.0f;
        for (int b = 1023; b >= 0; --b) {
            cum += hist[b];
            if (cum >= TOPK) { T = (float)b * (1.0f/512.0f) - 1.0f - 0.005f; break; }
        }
        Tsh = T;
        cnt[row] = 0;
    }
    __syncthreads();
    float T = Tsh;
    for (int c = t; c < MQ; c += 256) {
        const u16x8* kr = reinterpret_cast<const u16x8*>(k_hi + (long)c*128);
        float v = 0.f;
        for (int j = 0; j < 16; ++j) {
            u16x8 kv = kr[j];
            #pragma unroll
            for (int e = 0; e < 8; ++e) v += qr[j*8+e] * bf2f(kv[e]);
        }
        if (v >= T) {
            int pos = atomicAdd(&cnt[row], 1);
            if (pos < CAP) cand[row*CAP + pos] = c;
        }
    }
}

// ---------------- K4: exact f64 re-score, top-50, softmax, context ----------------
__global__ __launch_bounds__(256) void k_select(
        const double* __restrict__ q64, const float* __restrict__ Wk,
        const float* __restrict__ bk, const float* __restrict__ fq,
        const double* __restrict__ invn, const int* __restrict__ sq,
        const int* __restrict__ sid, const int* __restrict__ cnt,
        const int* __restrict__ cand,
        float* __restrict__ attn_g, int* __restrict__ tidx_g, int* __restrict__ used_g,
        float* __restrict__ out_ctx, float* __restrict__ out_used,
        const float* __restrict__ fb_ctx) {
    __shared__ double qs[128];
    __shared__ double wqr[128];
    __shared__ double qb_s;
    __shared__ double vals[CAP];
    __shared__ int cidx[CAP];
    __shared__ double selv[TOPK];
    __shared__ int seli[TOPK];
    __shared__ float attn_s[TOPK];
    __shared__ int used_s;
    int row = blockIdx.x, t = threadIdx.x;
    if (t < 128) qs[t] = q64[row*128 + t];
    __syncthreads();
    if (t < 128) {
        double s = 0.0;
        for (int d = 0; d < 128; ++d) s += (double)Wk[t*128 + d] * qs[d];
        wqr[t] = s;
    }
    if (t == 0) {
        double s = 0.0;
        for (int d = 0; d < 128; ++d) s += qs[d] * (double)bk[d];
        qb_s = s;
    }
    if (t < TOPK) { selv[t] = -1e290; seli[t] = 0; }
    __syncthreads();
    int n = cnt[row]; if (n > CAP) n = CAP;
    int myses = sid[row];
    for (int j = t; j < n; j += 256) {
        int c = cand[row*CAP + j];
        cidx[j] = c;
        double v;
        if (sq[c] == myses) v = -1e300;
        else {
            double s = qb_s;
            const float4* xr4 = reinterpret_cast<const float4*>(fq + (long)c*128);
            for (int i4 = 0; i4 < 32; ++i4) {
                float4 x4 = xr4[i4];
                s += (double)x4.x * wqr[i4*4+0] + (double)x4.y * wqr[i4*4+1]
                   + (double)x4.z * wqr[i4*4+2] + (double)x4.w * wqr[i4*4+3];
            }
            v = s * invn[c];
        }
        vals[j] = v;
    }
    __syncthreads();
    for (int j = t; j < n; j += 256) {
        double v = vals[j]; int ci = cidx[j];
        int rk = 0;
        for (int m2 = 0; m2 < n; ++m2) {
            double vm = vals[m2];
            rk += (vm > v) || (vm == v && cidx[m2] < ci);
        }
        if (rk < TOPK) { selv[rk] = v; seli[rk] = ci; }
    }
    __syncthreads();
    if (t == 0) {
        double vmax = -1.0e308;
        for (int r = 0; r < TOPK; ++r)
            if (selv[r] > -1e250 && selv[r] > vmax) vmax = selv[r];
        float ssum = 0.f;
        for (int r = 0; r < TOPK; ++r) {
            float ev = 0.f;
            if (selv[r] > -1e250) ev = expf((float)((selv[r] - vmax) * (1.0/0.07)));
            attn_s[r] = ev; ssum += ev;
        }
        float invs = (ssum > 0.f) ? 1.0f/ssum : 0.0f;
        for (int r = 0; r < TOPK; ++r) attn_s[r] *= invs;
        used_s = (ssum > 0.f) ? 1 : 0;
        used_g[row] = used_s;
    }
    __syncthreads();
    int used = used_s;
    if (t < TOPK) { attn_g[row*TOPK + t] = attn_s[t]; tidx_g[row*TOPK + t] = seli[t]; }
    if (t < 128) {
        float cacc = 0.f;
        for (int r = 0; r < TOPK; ++r) cacc += attn_s[r] * fq[(long)seli[r]*128 + t];
        out_ctx[row*128 + t] = used ? cacc : fb_ctx[t];
    }
    if (t == 0) out_used[row] = used ? 1.0f : 0.0f;
}

// ---------------- K5: fused MLP ----------------
__global__ __launch_bounds__(256) void k_mlp(
        const float* __restrict__ fq, const float* __restrict__ item_emb,
        const int* __restrict__ tq,
        const unsigned short* __restrict__ W1t, const unsigned short* __restrict__ W2t,
        const float* __restrict__ b1, const float* __restrict__ b2,
        const float* __restrict__ attn_g, const int* __restrict__ tidx_g,
        const int* __restrict__ used_g,
        const float* __restrict__ fb_sum, float* __restrict__ out_sum) {
    __shared__ __align__(16) unsigned short xs[64*256];
    __shared__ float attn_s[64];
    __shared__ int tgt_s[64];
    __shared__ int tix_s[64];
    int b = blockIdx.x, t = threadIdx.x;
    if (t < 64) {
        float a = 0.f; int ti = 0;
        if (t < TOPK) { a = attn_g[b*TOPK + t]; ti = tidx_g[b*TOPK + t]; }
        attn_s[t] = a; tix_s[t] = ti;
        int tg = 0;
        if (t < TOPK) { tg = tq[ti]; if (tg < 0) tg = 0; }
        tgt_s[t] = tg;
    }
    __syncthreads();
    for (int j = 0; j < 8; ++j) {
        int chunk = t + 256*j;
        int r = chunk >> 5, s = chunk & 31;
        int sp = s ^ (r & 7);
        u16x8 o = {0,0,0,0,0,0,0,0};
        if (r < TOPK) {
            int c0 = s * 8;
            const float* src = (c0 < 128) ? (fq + (long)tix_s[r]*128 + c0)
                                          : (item_emb + (long)tgt_s[r]*128 + (c0 - 128));
            float4 v0 = *reinterpret_cast<const float4*>(src);
            float4 v1 = *reinterpret_cast<const float4*>(src + 4);
            o[0] = f2bf(v0.x); o[1] = f2bf(v0.y); o[2] = f2bf(v0.z); o[3] = f2bf(v0.w);
            o[4] = f2bf(v1.x); o[5] = f2bf(v1.y); o[6] = f2bf(v1.z); o[7] = f2bf(v1.w);
        }
        *reinterpret_cast<u16x8*>(&xs[(r*32 + sp)*8]) = o;
    }
    __syncthreads();
    int w = t >> 6, l = t & 63, lr = l & 15, lk = l >> 4;
    int wbase = w * 64;
    f32x4 zero4 = {0.f, 0.f, 0.f, 0.f};
    f32x4 acc[4][4];
    #pragma unroll
    for (int rt = 0; rt < 4; ++rt)
        #pragma unroll
        for (int ctl = 0; ctl < 4; ++ctl) acc[rt][ctl] = zero4;
    #pragma unroll
    for (int kk = 0; kk < 8; ++kk) {
        bf16x8 av[4];
        #pragma unroll
        for (int rt = 0; rt < 4; ++rt) {
            int r = rt*16 + lr;
            int sp = (kk*4 + lk) ^ (r & 7);
            av[rt] = *reinterpret_cast<const bf16x8*>(&xs[(r*32 + sp)*8]);
        }
        #pragma unroll
        for (int ctl = 0; ctl < 4; ++ctl) {
            int col = wbase + ctl*16 + lr;
            bf16x8 bv = *reinterpret_cast<const bf16x8*>(&W1t[(long)col*256 + kk*32 + lk*8]);
            #pragma unroll
            for (int rt = 0; rt < 4; ++rt)
                acc[rt][ctl] = __builtin_amdgcn_mfma_f32_16x16x32_bf16(av[rt], bv, acc[rt][ctl], 0, 0, 0);
        }
    }
    __syncthreads();
    #pragma unroll
    for (int ctl = 0; ctl < 4; ++ctl) {
        int col = wbase + ctl*16 + lr;
        float b1v = b1[col];
        #pragma unroll
        for (int rt = 0; rt < 4; ++rt) {
            #pragma unroll
            for (int i = 0; i < 4; ++i) {
                int r = rt*16 + lk*4 + i;
                float v = acc[rt][ctl][i] + b1v;
                float g = 0.5f * v * (1.0f + erff(v * 0.70710678118654752f));
                int cchunk = (col >> 3) ^ (r & 7);
                xs[(r*32 + cchunk)*8 + (col & 7)] = f2bf(g);
            }
        }
    }
    __syncthreads();
    f32x4 acc2[4][4];
    #pragma unroll
    for (int rt = 0; rt < 4; ++rt)
        #pragma unroll
        for (int ctl = 0; ctl < 4; ++ctl) acc2[rt][ctl] = zero4;
    #pragma unroll
    for (int kk = 0; kk < 8; ++kk) {
        bf16x8 av[4];
        #pragma unroll
        for (int rt = 0; rt < 4; ++rt) {
            int r = rt*16 + lr;
            int sp = (kk*4 + lk) ^ (r & 7);
            av[rt] = *reinterpret_cast<const bf16x8*>(&xs[(r*32 + sp)*8]);
        }
        #pragma unroll
        for (int ctl = 0; ctl < 4; ++ctl) {
            int col = wbase + ctl*16 + lr;
            bf16x8 bv = *reinterpret_cast<const bf16x8*>(&W2t[(long)col*256 + kk*32 + lk*8]);
            #pragma unroll
            for (int rt = 0; rt < 4; ++rt)
                acc2[rt][ctl] = __builtin_amdgcn_mfma_f32_16x16x32_bf16(av[rt], bv, acc2[rt][ctl], 0, 0, 0);
        }
    }
    int used = used_g[b];
    #pragma unroll
    for (int ctl = 0; ctl < 4; ++ctl) {
        float ps = 0.f;
        #pragma unroll
        for (int rt = 0; rt < 4; ++rt)
            #pragma unroll
            for (int i = 0; i < 4; ++i)
                ps += attn_s[rt*16 + lk*4 + i] * acc2[rt][ctl][i];
        ps += __shfl_xor(ps, 16, 64);
        ps += __shfl_xor(ps, 32, 64);
        if (l < 16) {
            int col = wbase + ctl*16 + l;
            out_sum[b*256 + col] = used ? (ps + b2[col]) : fb_sum[col];
        }
    }
}

extern "C" void kernel_launch(void* const* d_in, const int* in_sizes, int n_in,
                              void* d_out, int out_size, void* d_ws, size_t ws_size,
                              hipStream_t stream) {
    const float* cr   = (const float*)d_in[0];
    const int*   sid  = (const int*)d_in[1];
    const float* item = (const float*)d_in[2];
    const float* fq   = (const float*)d_in[3];
    const int*   sq   = (const int*)d_in[4];
    const int*   tq   = (const int*)d_in[5];
    const float* Wq   = (const float*)d_in[6];
    const float* bq   = (const float*)d_in[7];
    const float* Wk   = (const float*)d_in[8];
    const float* bk   = (const float*)d_in[9];
    const float* W1   = (const float*)d_in[10];
    const float* b1   = (const float*)d_in[11];
    const float* W2   = (const float*)d_in[12];
    const float* b2   = (const float*)d_in[13];
    const float* fbc  = (const float*)d_in[14];
    const float* fbs  = (const float*)d_in[15];

    float* out_ctx  = (float*)d_out;
    float* out_sum  = out_ctx + 1024*128;
    float* out_used = out_sum + 1024*256;

    char* w = (char*)d_ws;
    unsigned short* k_hi = (unsigned short*)w;  w += (size_t)MQ*128*2;
    double* invn = (double*)w;                  w += (size_t)MQ*8;
    double* q64 = (double*)w;                   w += (size_t)1024*128*8;
    unsigned short* qbf = (unsigned short*)w;   w += (size_t)1024*128*2;
    unsigned short* W1t = (unsigned short*)w;   w += (size_t)256*256*2;
    unsigned short* W2t = (unsigned short*)w;   w += (size_t)256*256*2;
    int* cand = (int*)w;                        w += (size_t)1024*CAP*4;
    int* cnt = (int*)w;                         w += (size_t)1024*4;
    int* cnthi = (int*)w;                       w += (size_t)1024*4;
    float* attn_g = (float*)w;                  w += (size_t)1024*TOPK*4;
    int* tidx_g = (int*)w;                      w += (size_t)1024*TOPK*4;
    int* used_g = (int*)w;                      w += (size_t)1024*4;
    float* ws_s = (float*)w;                    w += (size_t)NS_BLK*2048*4;
    float* Trow = (float*)w;                    w += (size_t)1024*4;

    hipMemsetAsync(cnt, 0, 1024*4, stream);
    hipMemsetAsync(cnthi, 0, 1024*4, stream);
    k_transpose<<<512, 256, 0, stream>>>(W1, W2, W1t, W2t);
    k_qproj<<<1024, 128, 0, stream>>>(cr, Wq, bq, q64, qbf);
    k_kproj<<<(MQ + 127)/128, 256, 0, stream>>>(fq, Wk, bk, k_hi, invn);
    k_stats<<<dim3(NS_BLK, 8), 256, 0, stream>>>(qbf, k_hi, ws_s);
    k_thresh<<<4, 256, 0, stream>>>(ws_s, Trow);
    k_append<<<dim3(NAPP, 4), 256, 0, stream>>>(qbf, k_hi, Trow, sq, sid, cnt, cnthi, cand);
    k_fix<<<1024, 256, 0, stream>>>(qbf, k_hi, sq, sid, cnt, cnthi, cand);
    k_select<<<1024, 256, 0, stream>>>(q64, Wk, bk, fq, invn, sq, sid, cnt, cand,
                                       attn_g, tidx_g, used_g, out_ctx, out_used, fbc);
    k_mlp<<<1024, 256, 0, stream>>>(fq, item, tq, W1t, W2t, b1, b2,
                                    attn_g, tidx_g, used_g, fbs, out_sum);
}